// Round 20
// baseline (189.888 us; speedup 1.0000x reference)
//
#include <hip/hip_runtime.h>
#include <stdint.h>

typedef __bf16 bf16;
typedef bf16 bf16x8 __attribute__((ext_vector_type(8)));
typedef bf16 bf16x4 __attribute__((ext_vector_type(4)));
typedef float f32x2 __attribute__((ext_vector_type(2)));
typedef float f32x4 __attribute__((ext_vector_type(4)));
typedef float f32x16 __attribute__((ext_vector_type(16)));

#define AS1 __attribute__((address_space(1)))
#define AS3 __attribute__((address_space(3)))

__device__ __forceinline__ void gll16(const void* g, void* l) {
    __builtin_amdgcn_global_load_lds((const AS1 unsigned int*)g,
                                     (AS3 unsigned int*)l, 16, 0, 0);
}

// native RTNE f32->bf16
__device__ __forceinline__ bf16 f2bf(float x) { return (bf16)x; }

// single-instruction v_exp_f32 (2^x); avoids glibc __exp2f macro collision
__device__ __forceinline__ float fexp2(float x) { return __builtin_amdgcn_exp2f(x); }

// counted vmcnt wait (T4): literal immediate, memory-clobber stops reordering
#define WAITV(N) asm volatile("s_waitcnt vmcnt(" #N ")" ::: "memory")

// QK scale folded into Q projection: (1/(8+1e-6)) * log2(e)
#define QSCALE_LOG2E 0.18033685757f

// ---------------- weight casts ----------------
// z<4: transpose-cast via LDS 64x64 tile (coalesced both sides); z>=4: straight copy
__global__ void k_castw(const float* __restrict__ Wq, const float* __restrict__ Wk,
                        const float* __restrict__ Wv, const float* __restrict__ Wo,
                        const float* __restrict__ W1, const float* __restrict__ W2,
                        bf16* __restrict__ oq, bf16* __restrict__ ok, bf16* __restrict__ ov,
                        bf16* __restrict__ oo, bf16* __restrict__ o1, bf16* __restrict__ o2)
{
    __shared__ bf16 L[64][65];
    const int z = blockIdx.y;
    const int t = threadIdx.x;
    const float* src = z == 0 ? Wq : z == 1 ? Wk : z == 2 ? Wv : z == 3 ? Wo : z == 4 ? W1 : W2;
    bf16* dst = z == 0 ? oq : z == 1 ? ok : z == 2 ? ov : z == 3 ? oo : z == 4 ? o1 : o2;
    if (z < 4) {
        const int tr = blockIdx.x >> 3, tc = blockIdx.x & 7;   // 64x64 tile
        const int r = t >> 2, c0 = (t & 3) * 16;
#pragma unroll
        for (int i = 0; i < 4; ++i) {
            float4 v = *(const float4*)(src + (size_t)(tr * 64 + r) * 512 + tc * 64 + c0 + i * 4);
            L[r][c0 + i * 4 + 0] = f2bf(v.x);
            L[r][c0 + i * 4 + 1] = f2bf(v.y);
            L[r][c0 + i * 4 + 2] = f2bf(v.z);
            L[r][c0 + i * 4 + 3] = f2bf(v.w);
        }
        __syncthreads();
        const int c2 = t >> 2, r0 = (t & 3) * 16;
        bf16* d = dst + (size_t)(tc * 64 + c2) * 512 + tr * 64 + r0;
#pragma unroll
        for (int i = 0; i < 16; ++i) d[i] = L[r0 + i][c2];
    } else {
        const size_t base = (size_t)blockIdx.x * 4096 + t * 16;
#pragma unroll
        for (int i = 0; i < 4; ++i) {
            float4 v = *(const float4*)(src + base + i * 4);
            bf16x4 o;
            o[0] = f2bf(v.x); o[1] = f2bf(v.y); o[2] = f2bf(v.z); o[3] = f2bf(v.w);
            *(bf16x4*)(dst + base + i * 4) = o;
        }
    }
}

// ---------------- shared GEMM core (bf16 A): C[128,128] += A[M,K] * Bt[N,K]^T ----------------
__device__ __forceinline__ void gemm_core(const bf16* __restrict__ A,
                                          const bf16* __restrict__ Bt,
                                          const int K, bf16* As, bf16* Bs,
                                          const int bm, const int bn,
                                          f32x4 acc[4][4])
{
    const int tid  = threadIdx.x;
    const int lane = tid & 63;
    const int wave = tid >> 6;
    const int g    = lane >> 4;
    const int l15  = lane & 15;
    const int wm   = (wave >> 1) * 64;
    const int wn   = (wave & 1) * 64;

    const int srow = tid >> 2;
    const int sk   = (tid & 3) * 8;
    const size_t aoff0 = (size_t)(bm + srow) * K + sk;
    const size_t aoff1 = (size_t)(bm + 64 + srow) * K + sk;
    const size_t boff0 = (size_t)(bn + srow) * K + sk;
    const size_t boff1 = (size_t)(bn + 64 + srow) * K + sk;
    char* asb = (char*)As + wave * 1024;
    char* bsb = (char*)Bs + wave * 1024;

    for (int kt = 0; kt < K; kt += 32) {
        __syncthreads();
        gll16(A + aoff0 + kt, asb);
        gll16(A + aoff1 + kt, asb + 4096);
        gll16(Bt + boff0 + kt, bsb);
        gll16(Bt + boff1 + kt, bsb + 4096);
        __syncthreads();
        bf16x8 af[4], bfv[4];
#pragma unroll
        for (int mi = 0; mi < 4; ++mi)
            af[mi] = *(const bf16x8*)&As[(wm + mi * 16 + l15) * 32 + g * 8];
#pragma unroll
        for (int ni = 0; ni < 4; ++ni)
            bfv[ni] = *(const bf16x8*)&Bs[(wn + ni * 16 + l15) * 32 + g * 8];
#pragma unroll
        for (int mi = 0; mi < 4; ++mi)
#pragma unroll
            for (int ni = 0; ni < 4; ++ni)
                acc[mi][ni] = __builtin_amdgcn_mfma_f32_16x16x32_bf16(
                    af[mi], bfv[ni], acc[mi][ni], 0, 0, 0);
    }
}

// ---------------- generic epilogue GEMMs ----------------
// EPI 1: Cb = bf16(acc + residf)                  (W_o + fp32 Q residual -> Xbf)
// EPI 2: Cb = bf16(relu(acc + bias[col]))         (FFN1 -> H1)
// EPI 3: Cf = acc + bias[col] + float(residb)     (FFN2 + residual -> out)
template<int EPI>
__global__ __launch_bounds__(256)
void k_gemm(const bf16* __restrict__ A, const bf16* __restrict__ Bt,
            const float* __restrict__ bias, const float* __restrict__ residf,
            const bf16* __restrict__ residb,
            float* __restrict__ Cf, bf16* __restrict__ Cb,
            int M, int N, int K)
{
    __shared__ bf16 As[128 * 32];
    __shared__ bf16 Bs[128 * 32];
    const int bm = blockIdx.y * 128, bn = blockIdx.x * 128;
    f32x4 acc[4][4] = {};
    gemm_core(A, Bt, K, As, Bs, bm, bn, acc);

    const int tid  = threadIdx.x;
    const int lane = tid & 63;
    const int wave = tid >> 6;
    const int g    = lane >> 4;
    const int l15  = lane & 15;
    const int wm   = (wave >> 1) * 64;
    const int wn   = (wave & 1) * 64;
    const int col0 = bn + wn + l15;
#pragma unroll
    for (int ni = 0; ni < 4; ++ni) {
        const int col = col0 + ni * 16;
        float bv = 0.f;
        if constexpr (EPI == 2 || EPI == 3) bv = bias[col];
#pragma unroll
        for (int mi = 0; mi < 4; ++mi) {
#pragma unroll
            for (int r = 0; r < 4; ++r) {
                const int row = bm + wm + mi * 16 + 4 * g + r;
                const size_t idx = (size_t)row * N + col;
                float v = acc[mi][ni][r];
                if constexpr (EPI == 1) {
                    Cb[idx] = f2bf(v + residf[idx]);
                } else if constexpr (EPI == 2) {
                    Cb[idx] = f2bf(fmaxf(v + bv, 0.f));
                } else {
                    Cf[idx] = v + bv + (float)residb[idx];
                }
            }
        }
    }
}

// ---------------- fused cast+projection, depth-1 counted-vmcnt pipeline (round-19) ----------------
__global__ __launch_bounds__(256)
void k_proj(const float* __restrict__ Qf, const float* __restrict__ Kf, const float* __restrict__ Vf,
            const bf16* __restrict__ BQ, const bf16* __restrict__ BK, const bf16* __restrict__ BV,
            bf16* __restrict__ OQ, bf16* __restrict__ OK_, bf16* __restrict__ OV)
{
    __shared__ char SMRAW[49152];        // 2 bufs x (16KB fp32 A + 8KB bf16 B)

    // XCD-grouped decode: x = XCD slot, 4 bn-blocks of one (z,bm) adjacent per XCD
    const int dd = blockIdx.x;
    const int x = dd & 7, q = dd >> 3;
    const int bnb = q & 3;
    const int tt = x * 48 + (q >> 2);    // 0..383
    const int z  = tt >> 7;
    const int bm = (tt & 127) * 128;
    const int bn = bnb * 128;

    const float* A = z == 0 ? Qf : z == 1 ? Kf : Vf;
    const bf16* Bt = z == 0 ? BQ : z == 1 ? BK : BV;
    bf16* Cb       = z == 0 ? OQ : z == 1 ? OK_ : OV;

    const int tid  = threadIdx.x;
    const int lane = tid & 63;
    const int wave = tid >> 6;
    const int g    = lane >> 4;
    const int l15  = lane & 15;
    const int wm   = (wave >> 1) * 64;
    const int wn   = (wave & 1) * 64;

    const int krow = tid >> 3, kc = tid & 7;
    const size_t aoff = (size_t)(bm + krow) * 512 + ((kc ^ (krow & 7)) << 2);
    const int srow = tid >> 2;
    const int sk   = (tid & 3) * 8;
    const size_t boff0 = (size_t)(bn + srow) * 512 + sk;
    const size_t boff1 = (size_t)(bn + 64 + srow) * 512 + sk;

    f32x4 acc[4][4] = {};

    auto stageF = [&](int s, char* buf) {   // 6 gll16/thread per stage
        const int kt = s * 32;
#pragma unroll
        for (int j = 0; j < 4; ++j)
            gll16(A + aoff + j * 16384 + kt, buf + j * 4096 + tid * 16);
        gll16(Bt + boff0 + kt, buf + 16384 + wave * 1024);
        gll16(Bt + boff1 + kt, buf + 16384 + 4096 + wave * 1024);
    };

    auto computeF = [&](const char* buf) {
        bf16x8 af[4], bfv[4];
#pragma unroll
        for (int mi = 0; mi < 4; ++mi) {
            const int row = wm + mi * 16 + l15;
            const int r7 = row & 7;
            float4 lo = *(const float4*)(buf + row * 128 + (((2 * g) ^ r7) << 4));
            float4 hi = *(const float4*)(buf + row * 128 + (((2 * g + 1) ^ r7) << 4));
            af[mi][0] = f2bf(lo.x); af[mi][1] = f2bf(lo.y);
            af[mi][2] = f2bf(lo.z); af[mi][3] = f2bf(lo.w);
            af[mi][4] = f2bf(hi.x); af[mi][5] = f2bf(hi.y);
            af[mi][6] = f2bf(hi.z); af[mi][7] = f2bf(hi.w);
        }
#pragma unroll
        for (int ni = 0; ni < 4; ++ni)
            bfv[ni] = *(const bf16x8*)(buf + 16384 +
                        ((wn + ni * 16 + l15) * 32 + g * 8) * 2);
#pragma unroll
        for (int mi = 0; mi < 4; ++mi)
#pragma unroll
            for (int ni = 0; ni < 4; ++ni)
                acc[mi][ni] = __builtin_amdgcn_mfma_f32_16x16x32_bf16(
                    af[mi], bfv[ni], acc[mi][ni], 0, 0, 0);
    };

    // prologue: stage(0) in flight
    stageF(0, SMRAW);
#pragma unroll
    for (int t = 0; t < 16; ++t) {
        if (t + 1 < 16) {
            stageF(t + 1, SMRAW + ((t + 1) & 1) * 24576);
            WAITV(6);                        // stage(t) complete; t+1 stays in flight
        } else {
            WAITV(0);                        // final stage drain
        }
        __builtin_amdgcn_s_barrier();        // all waves' stage(t) writes visible
        __builtin_amdgcn_sched_barrier(0);
        computeF(SMRAW + (t & 1) * 24576);
        __builtin_amdgcn_s_barrier();        // nobody still reads buf(t) when t+2 overwrites
    }

    // ---- epilogue: LDS-image scatter + contiguous copy-out ----
    const int bb = bm >> 11;         // batch
    const int s0 = bm & 2047;        // 128-aligned sequence base
    __syncthreads();                 // full fence before reusing SMRAW as image
#pragma unroll
    for (int p = 0; p < 2; ++p) {
        if ((wave >> 1) == p) {
            if (z == 0) {
#pragma unroll
                for (int ni = 0; ni < 4; ++ni) {
                    const int col = wn + ni * 16 + l15;   // block-local column
                    const int hh = col >> 6, dk = col & 63;
                    char* img = SMRAW + hh * 8192;
#pragma unroll
                    for (int mi = 0; mi < 4; ++mi)
#pragma unroll
                        for (int r = 0; r < 4; ++r) {
                            const int sl = mi * 16 + 4 * g + r;
                            *(bf16*)(img + (sl * 64 + dk) * 2) =
                                f2bf(acc[mi][ni][r] * QSCALE_LOG2E);
                        }
                }
            } else if (z == 1) {
#pragma unroll
                for (int ni = 0; ni < 4; ++ni) {
                    const int col = wn + ni * 16 + l15;
                    const int hh = col >> 6, dk = col & 63;
                    const int ks = dk >> 4, h2 = (dk >> 3) & 1, e = dk & 7;
                    char* img = SMRAW + hh * 8192;
#pragma unroll
                    for (int mi = 0; mi < 4; ++mi)
#pragma unroll
                        for (int r = 0; r < 4; ++r) {
                            const int sl = mi * 16 + 4 * g + r;
                            const int t2 = sl >> 5, ql = sl & 31;
                            *(bf16*)(img + (((t2 * 4 + ks) * 64 + h2 * 32 + ql) * 8 + e) * 2) =
                                f2bf(acc[mi][ni][r]);
                        }
                }
            } else {
#pragma unroll
                for (int ni = 0; ni < 4; ++ni) {
                    const int col = wn + ni * 16 + l15;
                    const int hh = col >> 6, dv = col & 63;
                    const int dvt = dv >> 5, ql = dv & 31;
                    char* img = SMRAW + hh * 8192;
#pragma unroll
                    for (int mi = 0; mi < 4; ++mi)
#pragma unroll
                        for (int r = 0; r < 4; ++r) {
                            const int sl = mi * 16 + 4 * g + r;
                            const int ktile = sl >> 4, kk = sl & 15;
                            const int h2 = (kk >> 2) & 1;
                            const int e = (kk & 3) | ((kk >> 3) << 2);
                            *(bf16*)(img + (((dvt * 4 + ktile) * 64 + h2 * 32 + ql) * 8 + e) * 2) =
                                f2bf(acc[mi][ni][r]);
                        }
                }
            }
        }
        __syncthreads();
        {   // linear copy-out: 256 threads x 4 x (b128 read + 16B store)
            const int hh = tid >> 7, t = tid & 127;
            const int hg = (bn >> 6) + hh;              // GLOBAL head index
            const size_t a0 = (size_t)(bb * 8 + hg) * 131072;
            const size_t slab = (z == 0) ? a0 + (size_t)(s0 + p * 64) * 64
                                         : a0 + (size_t)((s0 >> 6) + p) * 4096;
            const char* img = SMRAW + hh * 8192;
#pragma unroll
            for (int i = 0; i < 4; ++i) {
                const int G = i * 128 + t;
                bf16x8 vv = *(const bf16x8*)(img + G * 16);
                *(bf16x8*)&Cb[slab + (size_t)G * 8] = vv;
            }
        }
        if (p == 0) __syncthreads();
    }
}

// ---------------- flash attention, swapped 32x32, QBLK=64/wave ----------------
// K-loop now uses counted-vmcnt (T4): stage(t+1) stays in flight across barriers;
// no vmcnt(0) drain in steady state (4 gll16/thread/stage -> WAITV(4)).
__global__ __launch_bounds__(256, 2)
void k_attn(const bf16* __restrict__ Qp, const bf16* __restrict__ Khp,
            const bf16* __restrict__ Vtp, bf16* __restrict__ O)
{
    __shared__ bf16 smem[16384];   // 2 bufs x (8KB K + 8KB V)
    const int tid = threadIdx.x;
    const int l   = tid & 63;
    const int w   = tid >> 6;
    const int h   = l >> 5;
    const int ql  = l & 31;
    // XCD-chunked swizzle: xcd = d&7; 8 bh per XCD (K+V = 4MB, L2-resident)
    const int d   = blockIdx.x;
    const int bh  = ((d >> 6) << 3) | (d & 7);
    const int qt  = (d >> 3) & 7;
    const size_t base = (size_t)bh * 131072;
    const int q0 = qt * 256 + w * 64;
    const int loff = l * 16;

    // Q fragments (B-operand), two 32-row groups
    bf16x8 qfA[4], qfB[4];
#pragma unroll
    for (int ks = 0; ks < 4; ++ks) {
        qfA[ks] = *(const bf16x8*)&Qp[base + (size_t)(q0 + ql) * 64 + ks * 16 + h * 8];
        qfB[ks] = *(const bf16x8*)&Qp[base + (size_t)(q0 + 32 + ql) * 64 + ks * 16 + h * 8];
    }

    f32x16 oA0 = {}, oA1 = {}, oB0 = {}, oB1 = {};
    float lrunA = 0.f, lrunB = 0.f;

    const bf16* ksrc = Khp + base + tid * 8;
    const bf16* vsrc = Vtp + base + tid * 8;
    char* kb0 = (char*)smem;
    char* kb1 = (char*)smem + 16384;
    const int wdst = w * 1024;

    auto stage = [&](int kvt, char* kb) {   // 4 gll16/thread per tile
        const bf16* ks = ksrc + kvt * 4096;
        const bf16* vs = vsrc + kvt * 4096;
        gll16(ks,        kb + wdst);
        gll16(ks + 2048, kb + 4096 + wdst);
        gll16(vs,        kb + 8192 + wdst);
        gll16(vs + 2048, kb + 12288 + wdst);
    };

    auto compute = [&](const char* kb) {
        // ---- S^T = K Q^T : each A-fragment read feeds both q-groups ----
        f32x16 sA0 = {}, sA1 = {}, sB0 = {}, sB1 = {};
        __builtin_amdgcn_s_setprio(1);
#pragma unroll
        for (int ks = 0; ks < 4; ++ks) {
            bf16x8 a0 = *(const bf16x8*)(kb + ks * 1024 + loff);
            bf16x8 a1 = *(const bf16x8*)(kb + 4096 + ks * 1024 + loff);
            sA0 = __builtin_amdgcn_mfma_f32_32x32x16_bf16(a0, qfA[ks], sA0, 0, 0, 0);
            sB0 = __builtin_amdgcn_mfma_f32_32x32x16_bf16(a0, qfB[ks], sB0, 0, 0, 0);
            sA1 = __builtin_amdgcn_mfma_f32_32x32x16_bf16(a1, qfA[ks], sA1, 0, 0, 0);
            sB1 = __builtin_amdgcn_mfma_f32_32x32x16_bf16(a1, qfB[ks], sB1, 0, 0, 0);
        }
        __builtin_amdgcn_s_setprio(0);

        // ---- exp2 (native v_exp_f32) + packed lane-local partial sums ----
        f32x2 pA = {0.f, 0.f}, pB = {0.f, 0.f};
#pragma unroll
        for (int r = 0; r < 16; r += 2) {
            sA0[r]     = fexp2(sA0[r]);
            sA0[r + 1] = fexp2(sA0[r + 1]);
            sA1[r]     = fexp2(sA1[r]);
            sA1[r + 1] = fexp2(sA1[r + 1]);
            pA += (f32x2){sA0[r], sA0[r + 1]};
            pA += (f32x2){sA1[r], sA1[r + 1]};
        }
#pragma unroll
        for (int r = 0; r < 16; r += 2) {
            sB0[r]     = fexp2(sB0[r]);
            sB0[r + 1] = fexp2(sB0[r + 1]);
            sB1[r]     = fexp2(sB1[r]);
            sB1[r + 1] = fexp2(sB1[r + 1]);
            pB += (f32x2){sB0[r], sB0[r + 1]};
            pB += (f32x2){sB1[r], sB1[r + 1]};
        }
        lrunA += pA[0] + pA[1];
        lrunB += pB[0] + pB[1];

        // ---- P fragments (C/D order -> B operand) ----
        bf16x8 pbA[4], pbB[4];
#pragma unroll
        for (int j = 0; j < 4; ++j) {
            const int ofs = 8 * (j & 1);
#pragma unroll
            for (int e = 0; e < 8; ++e) {
                pbA[j][e] = f2bf((j & 2) ? sA1[ofs + e] : sA0[ofs + e]);
                pbB[j][e] = f2bf((j & 2) ? sB1[ofs + e] : sB0[ofs + e]);
            }
        }

        // ---- O^T += V^T P : each V-fragment read feeds both q-groups ----
        const char* vr = kb + 8192;
        __builtin_amdgcn_s_setprio(1);
#pragma unroll
        for (int j = 0; j < 4; ++j) {
            bf16x8 a0 = *(const bf16x8*)(vr + j * 1024 + loff);
            bf16x8 a1 = *(const bf16x8*)(vr + 4096 + j * 1024 + loff);
            oA0 = __builtin_amdgcn_mfma_f32_32x32x16_bf16(a0, pbA[j], oA0, 0, 0, 0);
            oB0 = __builtin_amdgcn_mfma_f32_32x32x16_bf16(a0, pbB[j], oB0, 0, 0, 0);
            oA1 = __builtin_amdgcn_mfma_f32_32x32x16_bf16(a1, pbA[j], oA1, 0, 0, 0);
            oB1 = __builtin_amdgcn_mfma_f32_32x32x16_bf16(a1, pbB[j], oB1, 0, 0, 0);
        }
        __builtin_amdgcn_s_setprio(0);
    };

    // ---- T4 depth-1 pipeline: stage(t+1) in flight across the barrier pair ----
    stage(0, kb0);
    for (int t = 0; t < 32; ++t) {
        char* cur = (t & 1) ? kb1 : kb0;
        char* nxt = (t & 1) ? kb0 : kb1;
        if (t + 1 < 32) {
            stage(t + 1, nxt);
            WAITV(4);                        // stage(t) complete; t+1 stays in flight
        } else {
            WAITV(0);                        // final tile drain
        }
        __builtin_amdgcn_s_barrier();        // all waves' stage(t) writes visible
        __builtin_amdgcn_sched_barrier(0);
        compute(cur);
        __builtin_amdgcn_s_barrier();        // nobody still reads buf(t) when t+2 overwrites
    }

    // ---- epilogue per q-group: normalize, transpose via per-wave LDS, store ----
    char* ot = (char*)smem + w * 4096;
    const int qr = l >> 1;
    const int dh4 = (l & 1) * 4;
    auto epi = [&](const f32x16& e0, const f32x16& e1, float lr, int qg) {
        lr += __shfl_xor(lr, 32);
        const float inv = 1.f / lr;
#pragma unroll
        for (int dvt = 0; dvt < 2; ++dvt) {
#pragma unroll
            for (int r = 0; r < 16; ++r) {
                const int dv = dvt * 32 + (r & 3) + 8 * (r >> 2) + 4 * h;
                const float val = (dvt ? e1[r] : e0[r]) * inv;
                *(bf16*)(ot + ql * 128 + ((((dv >> 3) ^ (ql & 7)) << 4) | ((dv & 7) << 1))) = f2bf(val);
            }
        }
        const size_t ob = ((size_t)(bh >> 3) * 2048 + qg + qr) * 512 + (bh & 7) * 64 + (size_t)dh4 * 8;
#pragma unroll
        for (int B = 0; B < 4; ++B) {
            bf16x8 v = *(const bf16x8*)(ot + qr * 128 + (((dh4 + B) ^ (qr & 7)) << 4));
            *(bf16x8*)&O[ob + B * 8] = v;
        }
    };
    epi(oA0, oA1, lrunA, q0);
    epi(oB0, oB1, lrunB, q0 + 32);
}

// ---------------- launch ----------------
extern "C" void kernel_launch(void* const* d_in, const int* in_sizes, int n_in,
                              void* d_out, int out_size, void* d_ws, size_t ws_size,
                              hipStream_t stream)
{
    const float* Q  = (const float*)d_in[0];
    const float* K  = (const float*)d_in[1];
    const float* V  = (const float*)d_in[2];
    const float* Wq = (const float*)d_in[3];
    const float* Wk = (const float*)d_in[4];
    const float* Wv = (const float*)d_in[5];
    const float* Wo = (const float*)d_in[6];
    const float* W1 = (const float*)d_in[7];
    const float* b1 = (const float*)d_in[8];
    const float* W2 = (const float*)d_in[9];
    const float* b2 = (const float*)d_in[10];
    float* out = (float*)d_out;

    const int M = 8 * 2048;                 // 16384 rows
    const size_t TN = (size_t)M * 512;      // 8388608 elems
    const int WN = 512 * 512;               // 262144

    char* ws = (char*)d_ws;
    bf16* Qhp  = (bf16*)ws;  // head-split, scaled
    bf16* Khp  = Qhp + TN;   // fragment-ordered K
    bf16* Vtp  = Khp + TN;   // fragment-ordered transposed V
    bf16* Vatt = Vtp + TN;
    bf16* H1   = Vatt + TN;
    bf16* Xbf  = H1 + TN;
    bf16* Wqt  = Xbf + TN;
    bf16* Wkt  = Wqt + WN;
    bf16* Wvt  = Wkt + WN;
    bf16* Wot  = Wvt + WN;
    bf16* W1b  = Wot + WN;
    bf16* W2b  = W1b + WN;

    // weight casts (LDS tile transpose, coalesced)
    k_castw<<<dim3(64, 6), 256, 0, stream>>>(Wq, Wk, Wv, Wo, W1, W2,
                                             Wqt, Wkt, Wvt, Wot, W1b, W2b);

    // fused cast+projections, depth-1 counted-vmcnt pipeline, XCD-grouped (1536 blocks)
    k_proj<<<1536, 256, 0, stream>>>(Q, K, V, Wqt, Wkt, Wvt,
                                     Qhp, Khp, Vtp);

    // attention (512 blocks, 2/CU), counted-vmcnt K-loop
    k_attn<<<512, 256, 0, stream>>>(Qhp, Khp, Vtp, Vatt);

    dim3 gg(4, 128);
    // W_o + residual(Q fp32) -> Xbf
    k_gemm<1><<<gg, 256, 0, stream>>>(Vatt, Wot, nullptr, Q, nullptr, nullptr, Xbf, M, 512, 512);
    // FFN1: relu(Xbf W1^T + b1) -> H1
    k_gemm<2><<<gg, 256, 0, stream>>>(Xbf, W1b, b1, nullptr, nullptr, nullptr, H1, M, 512, 512);
    // FFN2: H1 W2^T + b2 + Xbf -> out
    k_gemm<3><<<gg, 256, 0, stream>>>(H1, W2b, b2, nullptr, Xbf, out, nullptr, M, 512, 512);
}